// Round 16
// baseline (1017.982 us; speedup 1.0000x reference)
//
#include <hip/hip_runtime.h>
#include <stddef.h>
#include <stdint.h>

// Elman RNN: out[t,b,u] = h_t = tanh(x_t @ Wx + h_{t-1} @ Wh + bias)
// B=128, T=512, D=128, U=512. Output [T, B, U] float32.
//
// pgemm (f16 dot2): P = x@Wx + bias -> d_out. (~15 us, validated)
// rnn (builtin MFMA, r13 structure + r16 deferred stores): one WG (512 thr,
//   8 waves) per batch row. Wave w owns cols [64w, 64w+64) = 4 col-tiles.
//   64 MFMAs/wave/step; W = 48 frags register-resident (pinned) + 16 in LDS.
//   r16 change vs r13 (836 us): global h-stores moved AFTER __syncthreads —
//   they have no LDS dependency (h continuity is via hbuf), so their ~400cy
//   ack latency drains under the NEXT step's MFMA phase instead of inside
//   the pre-barrier vmcnt(0) drain. (r15 showed hoisting the prefetch LOADS
//   to the top regresses — loads stay in the tail, overlapping tanh.)
//   History: r14 hybrid fdot2 regressed (AGPR move tax); r11/r12 inline-asm
//   MFMA miscompiled; r13 pin killed W remat (FETCH 92.5->72.3 MB).
//   Layouts (validated r10/r13, absmax 0.0039):
//     A[i][k]: lane = i + 16*(k/8), elem = k%8   (row 0 broadcast to all i)
//     B[k][j]: lane = j + 16*(k/8), elem = k%8
//     D[i][j]: lane = j + 16*(i/4), reg = i%4    (row 0 -> lanes 0-15, .x)

constexpr int B = 128;
constexpr int T = 512;
constexpr int D = 128;
constexpr int U = 512;

typedef _Float16 f16;
typedef _Float16 f16x2 __attribute__((ext_vector_type(2)));
typedef _Float16 f16x8 __attribute__((ext_vector_type(8)));
typedef __fp16   fp16x2 __attribute__((ext_vector_type(2)));
typedef float    f32x4 __attribute__((ext_vector_type(4)));
typedef unsigned int u32;

union U32H2 { u32 u; f16x2 h; fp16x2 p; };

static __device__ __forceinline__ u32 pk(float a, float b) {
    U32H2 c; c.p = __builtin_amdgcn_cvt_pkrtz(a, b); return c.u;
}

#if __has_builtin(__builtin_amdgcn_fdot2)
static __device__ __forceinline__ float fdot2(u32 a, u32 b, float c) {
    U32H2 x, y; x.u = a; y.u = b;
    return __builtin_amdgcn_fdot2(x.h, y.h, c, false);
}
#else
static __device__ __forceinline__ float fdot2(u32 a, u32 b, float c) {
    U32H2 x, y; x.u = a; y.u = b;
    return c + (float)x.h.x * (float)y.h.x + (float)x.h.y * (float)y.h.y;
}
#endif

static __device__ __forceinline__ float fast_tanh(float x) {
    float e = __expf(2.0f * x);
    return 1.0f - 2.0f * __builtin_amdgcn_rcpf(e + 1.0f);
}

// ---------------------------------------------------------------------------
// Kernel 1: P = x @ Wx + bias  (M=T*B, K=D=128 one-shot, N=U) — f16 dot2
// ---------------------------------------------------------------------------
__global__ __launch_bounds__(256) void pgemm_kernel(
    const float* __restrict__ x,     // [B, T, D]
    const float* __restrict__ Wx,    // [D, U]
    const float* __restrict__ bias,  // [U]
    float* __restrict__ P)           // [T*B, U]  (== d_out)
{
    __shared__ u32 xs[128][66];      // [row][k-pair]   (+2 pad)
    __shared__ u32 ws[64][132];      // [k-pair][col]   (+4 pad)

    const int rb  = blockIdx.x;
    const int cb  = blockIdx.y;
    const int tid = threadIdx.x;
    const int tr  = tid >> 4;
    const int tcc = tid & 15;

    const float4* x4 = (const float4*)x;
#pragma unroll
    for (int l = 0; l < 16; ++l) {
        int idx = tid + l * 256;
        int r   = idx >> 5;
        int q   = idx & 31;
        int m   = rb * 128 + r;
        int b_  = m & 127;
        int t_  = m >> 7;
        float4 v = x4[((size_t)b_ * T + t_) * 32 + q];
        xs[r][2 * q]     = pk(v.x, v.y);
        xs[r][2 * q + 1] = pk(v.z, v.w);
    }
    const float4* W4 = (const float4*)Wx;
#pragma unroll
    for (int l = 0; l < 8; ++l) {
        int idx = tid + l * 256;
        int kp  = idx >> 5;
        int q   = idx & 31;
        float4 a = W4[(size_t)(2 * kp)     * 128 + cb * 32 + q];
        float4 c = W4[(size_t)(2 * kp + 1) * 128 + cb * 32 + q];
        uint4 w;
        w.x = pk(a.x, c.x); w.y = pk(a.y, c.y);
        w.z = pk(a.z, c.z); w.w = pk(a.w, c.w);
        *(uint4*)&ws[kp][4 * q] = w;
    }
    __syncthreads();

    float acc[8][8];
#pragma unroll
    for (int i = 0; i < 8; ++i)
#pragma unroll
        for (int j = 0; j < 8; ++j) acc[i][j] = 0.f;

#pragma unroll 2
    for (int kp = 0; kp < 64; ++kp) {
        u32 xv[8], wv[8];
#pragma unroll
        for (int i = 0; i < 8; ++i) xv[i] = xs[tr + 16 * i][kp];
#pragma unroll
        for (int j = 0; j < 8; ++j) wv[j] = ws[kp][tcc + 16 * j];
#pragma unroll
        for (int i = 0; i < 8; ++i)
#pragma unroll
            for (int j = 0; j < 8; ++j)
                acc[i][j] = fdot2(xv[i], wv[j], acc[i][j]);
    }

#pragma unroll
    for (int j = 0; j < 8; ++j) {
        int c    = cb * 128 + tcc + 16 * j;
        float bv = bias[c];
#pragma unroll
        for (int i = 0; i < 8; ++i) {
            int m = rb * 128 + tr + 16 * i;
            P[(size_t)m * U + c] = acc[i][j] + bv;
        }
    }
}

// ---------------------------------------------------------------------------
// Kernel 2: recurrence via MFMA, one WG (512 thr) per batch row.
// ---------------------------------------------------------------------------
__global__ __launch_bounds__(512, 2) void rnn_kernel(
    const float* __restrict__ Wh,    // [U, U] f32
    float* __restrict__ out)         // [T*B, U]; P on entry, h on exit
{
    __shared__ __align__(16) u32 WL[32768];      // 128 KB: W frags s=12..15
    __shared__ __align__(16) u32 hbuf[2][256];   // h f16 [2 parity][512]

    const int tid = threadIdx.x;
    const int w   = tid >> 6;        // wave 0..7 (owns cols 64w..64w+63)
    const int l   = tid & 63;        // lane
    const int lg  = l >> 4;          // k-octet group 0..3
    const int lc  = l & 15;          // col-in-tile
    const int b   = blockIdx.x;

    // ---- init: B-fragments of Wh (f32 -> f16) ----
    // frag(ct, s) elem e = Wh[32s + 8*lg + e][64w + 16ct + lc]
    f16x8 Wf[4][12];                 // slabs 0..11 -> register-resident
#pragma unroll
    for (int ct = 0; ct < 4; ++ct) {
#pragma unroll
        for (int s = 0; s < 12; ++s) {
            const float* src = Wh + (size_t)(32 * s + 8 * lg) * U
                             + 64 * w + 16 * ct + lc;
            f16x8 f;
#pragma unroll
            for (int e = 0; e < 8; ++e) f[e] = (f16)src[(size_t)e * U];
            Wf[ct][s] = f;
        }
    }
    // PIN: opaque def -> compiler cannot rematerialize Wf from global inside
    // the t-loop (round 10's hidden cost: FETCH 92.5MB = per-step W reloads).
#pragma unroll
    for (int ct = 0; ct < 4; ++ct)
#pragma unroll
        for (int s = 0; s < 12; ++s)
            asm("" : "+v"(Wf[ct][s]));

    // slabs 12..15 -> LDS, slot = (w*16 + sr*4 + ct), 16 B per lane
#pragma unroll
    for (int sr = 0; sr < 4; ++sr) {
#pragma unroll
        for (int ct = 0; ct < 4; ++ct) {
            const float* src = Wh + (size_t)(32 * (12 + sr) + 8 * lg) * U
                             + 64 * w + 16 * ct + lc;
            f16x8 f;
#pragma unroll
            for (int e = 0; e < 8; ++e) f[e] = (f16)src[(size_t)e * U];
            *(f16x8*)&WL[((w * 16 + sr * 4 + ct) * 64 + l) * 4] = f;
        }
    }

    if (tid < 256) { hbuf[0][tid] = 0u; hbuf[1][tid] = 0u; }
    __syncthreads();

    float* outb = out + (size_t)b * U;

    // P prefetch for t=0 (lanes 0-15 of each wave own cols 64w+16ct+lc)
    float pv0 = 0.f, pv1 = 0.f, pv2 = 0.f, pv3 = 0.f;
    if (l < 16) {
        pv0 = outb[64 * w + 0  + lc];
        pv1 = outb[64 * w + 16 + lc];
        pv2 = outb[64 * w + 32 + lc];
        pv3 = outb[64 * w + 48 + lc];
    }

    for (int t = 0; t < T; ++t) {
        const int par = t & 1;
        const f16* hb = (const f16*)hbuf[par];

        f32x4 acc0 = (f32x4)0.f, acc1 = (f32x4)0.f;
        f32x4 acc2 = (f32x4)0.f, acc3 = (f32x4)0.f;

        // A-frag: whole-wave broadcast of h octet (rows 1..15 of A are
        // harmless copies; only D row 0 is consumed).
#define ALOAD(s) (*(const f16x8*)&hb[32 * (s) + 8 * lg])
#define WLREAD(fi) (*(const f16x8*)&WL[((w * 16 + (fi)) * 64 + l) * 4])

        // 4 groups: {issue 4 LDS frag reads} {3 register slabs} {consume}
#pragma unroll
        for (int g = 0; g < 4; ++g) {
            f16x8 b0 = WLREAD(4 * g + 0);
            f16x8 b1 = WLREAD(4 * g + 1);
            f16x8 b2 = WLREAD(4 * g + 2);
            f16x8 b3 = WLREAD(4 * g + 3);
#pragma unroll
            for (int s = 3 * g; s < 3 * g + 3; ++s) {
                f16x8 a = ALOAD(s);
                acc0 = __builtin_amdgcn_mfma_f32_16x16x32_f16(a, Wf[0][s], acc0, 0, 0, 0);
                acc1 = __builtin_amdgcn_mfma_f32_16x16x32_f16(a, Wf[1][s], acc1, 0, 0, 0);
                acc2 = __builtin_amdgcn_mfma_f32_16x16x32_f16(a, Wf[2][s], acc2, 0, 0, 0);
                acc3 = __builtin_amdgcn_mfma_f32_16x16x32_f16(a, Wf[3][s], acc3, 0, 0, 0);
            }
            f16x8 a = ALOAD(12 + g);
            acc0 = __builtin_amdgcn_mfma_f32_16x16x32_f16(a, b0, acc0, 0, 0, 0);
            acc1 = __builtin_amdgcn_mfma_f32_16x16x32_f16(a, b1, acc1, 0, 0, 0);
            acc2 = __builtin_amdgcn_mfma_f32_16x16x32_f16(a, b2, acc2, 0, 0, 0);
            acc3 = __builtin_amdgcn_mfma_f32_16x16x32_f16(a, b3, acc3, 0, 0, 0);
        }
#undef ALOAD
#undef WLREAD

        // tail: row 0 of D lives in lanes 0-15, reg .x
        float nv0 = 0.f, nv1 = 0.f, nv2 = 0.f, nv3 = 0.f;
        float h0 = 0.f, h1 = 0.f, h2 = 0.f, h3 = 0.f;
        if (l < 16) {
            // (1) issue next-step P prefetch FIRST — latency hides under the
            // tanh chain below instead of stalling the drain cold.
            const float* prown = outb + (size_t)((t + 1 < T) ? t + 1 : t) * (B * U);
            nv0 = prown[64 * w + 0  + lc];
            nv1 = prown[64 * w + 16 + lc];
            nv2 = prown[64 * w + 32 + lc];
            nv3 = prown[64 * w + 48 + lc];

            // (2) activation + LDS h-store (the only pre-barrier dependency)
            f16* hbn = (f16*)hbuf[par ^ 1];
            h0 = fast_tanh(pv0 + acc0.x);
            h1 = fast_tanh(pv1 + acc1.x);
            h2 = fast_tanh(pv2 + acc2.x);
            h3 = fast_tanh(pv3 + acc3.x);
            hbn[64 * w + 0  + lc] = (f16)h0;
            hbn[64 * w + 16 + lc] = (f16)h1;
            hbn[64 * w + 32 + lc] = (f16)h2;
            hbn[64 * w + 48 + lc] = (f16)h3;
        }

        __syncthreads();   // h(par^1) visible for next step

        // (3) r16: global h-stores AFTER the barrier — their ack latency
        // drains under the next step's MFMA phase, not in the drain window.
        if (l < 16) {
            float* prow = outb + (size_t)t * (B * U);
            prow[64 * w + 0  + lc] = h0;
            prow[64 * w + 16 + lc] = h1;
            prow[64 * w + 32 + lc] = h2;
            prow[64 * w + 48 + lc] = h3;
        }

        pv0 = nv0; pv1 = nv1; pv2 = nv2; pv3 = nv3;
    }
}

// ---------------------------------------------------------------------------
extern "C" void kernel_launch(void* const* d_in, const int* in_sizes, int n_in,
                              void* d_out, int out_size, void* d_ws, size_t ws_size,
                              hipStream_t stream)
{
    (void)d_ws; (void)ws_size; (void)in_sizes; (void)n_in; (void)out_size;
    const float* x    = (const float*)d_in[0];  // [B, T, D]
    const float* Wx   = (const float*)d_in[1];  // [D, U]
    const float* Wh   = (const float*)d_in[2];  // [U, U]
    const float* bias = (const float*)d_in[3];  // [U]
    float* out = (float*)d_out;                 // [T, B, U]

    pgemm_kernel<<<dim3((T * B) / 128, U / 128), 256, 0, stream>>>(x, Wx, bias, out);
    rnn_kernel<<<B, 512, 0, stream>>>(Wh, out);
}

// Round 17
// 839.610 us; speedup vs baseline: 1.2124x; 1.2124x over previous
//
#include <hip/hip_runtime.h>
#include <stddef.h>
#include <stdint.h>

// Elman RNN: out[t,b,u] = h_t = tanh(x_t @ Wx + h_{t-1} @ Wh + bias)
// B=128, T=512, D=128, U=512. Output [T, B, U] float32.
//
// pgemm (f16 dot2): P = x@Wx + bias -> d_out. (~15 us, validated)
// rnn: r13 structure EXACTLY (836 us best; r15/r16 source reorderings both
//   regressed -> schedule is a local optimum, don't touch instruction order).
//   r17 changes ONLY the barrier: __syncthreads() -> lgkmcnt(0) + raw
//   s_barrier. __syncthreads emits s_waitcnt vmcnt(0) before s_barrier,
//   draining the 4 HBM-cold nv P-loads (~900cy, L2-evicted 128MB buffer) and
//   4 h-store acks on the serial path EVERY step. Raw barrier keeps them in
//   flight across the barrier; the compiler's vmcnt wait at pv's use site
//   lands a full MFMA phase (~2500cy) later. LDS correctness: hbuf parity
//   dbuf needs only lgkmcnt(0)+s_barrier (reads of par during step t finish
//   before the end-of-t barrier; writes target par^1). No global RAW crosses
//   the barrier (step t reads P[t+1], writes h[t], per-WG disjoint).
//   Layouts (validated r10/r13, absmax 0.0039):
//     A[i][k]: lane = i + 16*(k/8), elem = k%8   (row 0 broadcast to all i)
//     B[k][j]: lane = j + 16*(k/8), elem = k%8
//     D[i][j]: lane = j + 16*(i/4), reg = i%4    (row 0 -> lanes 0-15, .x)

constexpr int B = 128;
constexpr int T = 512;
constexpr int D = 128;
constexpr int U = 512;

typedef _Float16 f16;
typedef _Float16 f16x2 __attribute__((ext_vector_type(2)));
typedef _Float16 f16x8 __attribute__((ext_vector_type(8)));
typedef __fp16   fp16x2 __attribute__((ext_vector_type(2)));
typedef float    f32x4 __attribute__((ext_vector_type(4)));
typedef unsigned int u32;

union U32H2 { u32 u; f16x2 h; fp16x2 p; };

static __device__ __forceinline__ u32 pk(float a, float b) {
    U32H2 c; c.p = __builtin_amdgcn_cvt_pkrtz(a, b); return c.u;
}

#if __has_builtin(__builtin_amdgcn_fdot2)
static __device__ __forceinline__ float fdot2(u32 a, u32 b, float c) {
    U32H2 x, y; x.u = a; y.u = b;
    return __builtin_amdgcn_fdot2(x.h, y.h, c, false);
}
#else
static __device__ __forceinline__ float fdot2(u32 a, u32 b, float c) {
    U32H2 x, y; x.u = a; y.u = b;
    return c + (float)x.h.x * (float)y.h.x + (float)x.h.y * (float)y.h.y;
}
#endif

static __device__ __forceinline__ float fast_tanh(float x) {
    float e = __expf(2.0f * x);
    return 1.0f - 2.0f * __builtin_amdgcn_rcpf(e + 1.0f);
}

// ---------------------------------------------------------------------------
// Kernel 1: P = x @ Wx + bias  (M=T*B, K=D=128 one-shot, N=U) — f16 dot2
// ---------------------------------------------------------------------------
__global__ __launch_bounds__(256) void pgemm_kernel(
    const float* __restrict__ x,     // [B, T, D]
    const float* __restrict__ Wx,    // [D, U]
    const float* __restrict__ bias,  // [U]
    float* __restrict__ P)           // [T*B, U]  (== d_out)
{
    __shared__ u32 xs[128][66];      // [row][k-pair]   (+2 pad)
    __shared__ u32 ws[64][132];      // [k-pair][col]   (+4 pad)

    const int rb  = blockIdx.x;
    const int cb  = blockIdx.y;
    const int tid = threadIdx.x;
    const int tr  = tid >> 4;
    const int tcc = tid & 15;

    const float4* x4 = (const float4*)x;
#pragma unroll
    for (int l = 0; l < 16; ++l) {
        int idx = tid + l * 256;
        int r   = idx >> 5;
        int q   = idx & 31;
        int m   = rb * 128 + r;
        int b_  = m & 127;
        int t_  = m >> 7;
        float4 v = x4[((size_t)b_ * T + t_) * 32 + q];
        xs[r][2 * q]     = pk(v.x, v.y);
        xs[r][2 * q + 1] = pk(v.z, v.w);
    }
    const float4* W4 = (const float4*)Wx;
#pragma unroll
    for (int l = 0; l < 8; ++l) {
        int idx = tid + l * 256;
        int kp  = idx >> 5;
        int q   = idx & 31;
        float4 a = W4[(size_t)(2 * kp)     * 128 + cb * 32 + q];
        float4 c = W4[(size_t)(2 * kp + 1) * 128 + cb * 32 + q];
        uint4 w;
        w.x = pk(a.x, c.x); w.y = pk(a.y, c.y);
        w.z = pk(a.z, c.z); w.w = pk(a.w, c.w);
        *(uint4*)&ws[kp][4 * q] = w;
    }
    __syncthreads();

    float acc[8][8];
#pragma unroll
    for (int i = 0; i < 8; ++i)
#pragma unroll
        for (int j = 0; j < 8; ++j) acc[i][j] = 0.f;

#pragma unroll 2
    for (int kp = 0; kp < 64; ++kp) {
        u32 xv[8], wv[8];
#pragma unroll
        for (int i = 0; i < 8; ++i) xv[i] = xs[tr + 16 * i][kp];
#pragma unroll
        for (int j = 0; j < 8; ++j) wv[j] = ws[kp][tcc + 16 * j];
#pragma unroll
        for (int i = 0; i < 8; ++i)
#pragma unroll
            for (int j = 0; j < 8; ++j)
                acc[i][j] = fdot2(xv[i], wv[j], acc[i][j]);
    }

#pragma unroll
    for (int j = 0; j < 8; ++j) {
        int c    = cb * 128 + tcc + 16 * j;
        float bv = bias[c];
#pragma unroll
        for (int i = 0; i < 8; ++i) {
            int m = rb * 128 + tr + 16 * i;
            P[(size_t)m * U + c] = acc[i][j] + bv;
        }
    }
}

// ---------------------------------------------------------------------------
// Kernel 2: recurrence via MFMA, one WG (512 thr) per batch row.
// ---------------------------------------------------------------------------
__global__ __launch_bounds__(512, 2) void rnn_kernel(
    const float* __restrict__ Wh,    // [U, U] f32
    float* __restrict__ out)         // [T*B, U]; P on entry, h on exit
{
    __shared__ __align__(16) u32 WL[32768];      // 128 KB: W frags s=12..15
    __shared__ __align__(16) u32 hbuf[2][256];   // h f16 [2 parity][512]

    const int tid = threadIdx.x;
    const int w   = tid >> 6;        // wave 0..7 (owns cols 64w..64w+63)
    const int l   = tid & 63;        // lane
    const int lg  = l >> 4;          // k-octet group 0..3
    const int lc  = l & 15;          // col-in-tile
    const int b   = blockIdx.x;

    // ---- init: B-fragments of Wh (f32 -> f16) ----
    // frag(ct, s) elem e = Wh[32s + 8*lg + e][64w + 16ct + lc]
    f16x8 Wf[4][12];                 // slabs 0..11 -> register-resident
#pragma unroll
    for (int ct = 0; ct < 4; ++ct) {
#pragma unroll
        for (int s = 0; s < 12; ++s) {
            const float* src = Wh + (size_t)(32 * s + 8 * lg) * U
                             + 64 * w + 16 * ct + lc;
            f16x8 f;
#pragma unroll
            for (int e = 0; e < 8; ++e) f[e] = (f16)src[(size_t)e * U];
            Wf[ct][s] = f;
        }
    }
    // PIN: opaque def -> compiler cannot rematerialize Wf from global inside
    // the t-loop (round 10's hidden cost: FETCH 92.5MB = per-step W reloads).
#pragma unroll
    for (int ct = 0; ct < 4; ++ct)
#pragma unroll
        for (int s = 0; s < 12; ++s)
            asm("" : "+v"(Wf[ct][s]));

    // slabs 12..15 -> LDS, slot = (w*16 + sr*4 + ct), 16 B per lane
#pragma unroll
    for (int sr = 0; sr < 4; ++sr) {
#pragma unroll
        for (int ct = 0; ct < 4; ++ct) {
            const float* src = Wh + (size_t)(32 * (12 + sr) + 8 * lg) * U
                             + 64 * w + 16 * ct + lc;
            f16x8 f;
#pragma unroll
            for (int e = 0; e < 8; ++e) f[e] = (f16)src[(size_t)e * U];
            *(f16x8*)&WL[((w * 16 + sr * 4 + ct) * 64 + l) * 4] = f;
        }
    }

    if (tid < 256) { hbuf[0][tid] = 0u; hbuf[1][tid] = 0u; }
    __syncthreads();

    float* outb = out + (size_t)b * U;

    // P prefetch for t=0 (lanes 0-15 of each wave own cols 64w+16ct+lc)
    float pv0 = 0.f, pv1 = 0.f, pv2 = 0.f, pv3 = 0.f;
    if (l < 16) {
        pv0 = outb[64 * w + 0  + lc];
        pv1 = outb[64 * w + 16 + lc];
        pv2 = outb[64 * w + 32 + lc];
        pv3 = outb[64 * w + 48 + lc];
    }

    for (int t = 0; t < T; ++t) {
        const int par = t & 1;
        const f16* hb = (const f16*)hbuf[par];

        f32x4 acc0 = (f32x4)0.f, acc1 = (f32x4)0.f;
        f32x4 acc2 = (f32x4)0.f, acc3 = (f32x4)0.f;

        // A-frag: whole-wave broadcast of h octet (rows 1..15 of A are
        // harmless copies; only D row 0 is consumed).
#define ALOAD(s) (*(const f16x8*)&hb[32 * (s) + 8 * lg])
#define WLREAD(fi) (*(const f16x8*)&WL[((w * 16 + (fi)) * 64 + l) * 4])

        // 4 groups: {issue 4 LDS frag reads} {3 register slabs} {consume}
#pragma unroll
        for (int g = 0; g < 4; ++g) {
            f16x8 b0 = WLREAD(4 * g + 0);
            f16x8 b1 = WLREAD(4 * g + 1);
            f16x8 b2 = WLREAD(4 * g + 2);
            f16x8 b3 = WLREAD(4 * g + 3);
#pragma unroll
            for (int s = 3 * g; s < 3 * g + 3; ++s) {
                f16x8 a = ALOAD(s);
                acc0 = __builtin_amdgcn_mfma_f32_16x16x32_f16(a, Wf[0][s], acc0, 0, 0, 0);
                acc1 = __builtin_amdgcn_mfma_f32_16x16x32_f16(a, Wf[1][s], acc1, 0, 0, 0);
                acc2 = __builtin_amdgcn_mfma_f32_16x16x32_f16(a, Wf[2][s], acc2, 0, 0, 0);
                acc3 = __builtin_amdgcn_mfma_f32_16x16x32_f16(a, Wf[3][s], acc3, 0, 0, 0);
            }
            f16x8 a = ALOAD(12 + g);
            acc0 = __builtin_amdgcn_mfma_f32_16x16x32_f16(a, b0, acc0, 0, 0, 0);
            acc1 = __builtin_amdgcn_mfma_f32_16x16x32_f16(a, b1, acc1, 0, 0, 0);
            acc2 = __builtin_amdgcn_mfma_f32_16x16x32_f16(a, b2, acc2, 0, 0, 0);
            acc3 = __builtin_amdgcn_mfma_f32_16x16x32_f16(a, b3, acc3, 0, 0, 0);
        }
#undef ALOAD
#undef WLREAD

        // tail: row 0 of D lives in lanes 0-15, reg .x  (r13 order, verbatim)
        float nv0 = 0.f, nv1 = 0.f, nv2 = 0.f, nv3 = 0.f;
        if (l < 16) {
            float* prow = outb + (size_t)t * (B * U);
            const float* prown = outb + (size_t)((t + 1 < T) ? t + 1 : t) * (B * U);
            f16* hbn = (f16*)hbuf[par ^ 1];

            float h0 = fast_tanh(pv0 + acc0.x);
            float h1 = fast_tanh(pv1 + acc1.x);
            float h2 = fast_tanh(pv2 + acc2.x);
            float h3 = fast_tanh(pv3 + acc3.x);
            prow[64 * w + 0  + lc] = h0;
            prow[64 * w + 16 + lc] = h1;
            prow[64 * w + 32 + lc] = h2;
            prow[64 * w + 48 + lc] = h3;
            hbn[64 * w + 0  + lc] = (f16)h0;
            hbn[64 * w + 16 + lc] = (f16)h1;
            hbn[64 * w + 32 + lc] = (f16)h2;
            hbn[64 * w + 48 + lc] = (f16)h3;

            nv0 = prown[64 * w + 0  + lc];
            nv1 = prown[64 * w + 16 + lc];
            nv2 = prown[64 * w + 32 + lc];
            nv3 = prown[64 * w + 48 + lc];
        }

        // r17: LDS-only barrier. lgkmcnt(0) makes hbuf writes visible; raw
        // s_barrier does NOT drain vmcnt -> the nv loads and h stores stay
        // in flight across the barrier and complete under the next step's
        // MFMA phase. (__syncthreads would force vmcnt(0): ~900cy HBM-cold
        // load latency exposed on the serial path every step.)
        asm volatile("s_waitcnt lgkmcnt(0)" ::: "memory");
        __builtin_amdgcn_s_barrier();
        __builtin_amdgcn_sched_barrier(0);

        pv0 = nv0; pv1 = nv1; pv2 = nv2; pv3 = nv3;
    }
}

// ---------------------------------------------------------------------------
extern "C" void kernel_launch(void* const* d_in, const int* in_sizes, int n_in,
                              void* d_out, int out_size, void* d_ws, size_t ws_size,
                              hipStream_t stream)
{
    (void)d_ws; (void)ws_size; (void)in_sizes; (void)n_in; (void)out_size;
    const float* x    = (const float*)d_in[0];  // [B, T, D]
    const float* Wx   = (const float*)d_in[1];  // [D, U]
    const float* Wh   = (const float*)d_in[2];  // [U, U]
    const float* bias = (const float*)d_in[3];  // [U]
    float* out = (float*)d_out;                 // [T, B, U]

    pgemm_kernel<<<dim3((T * B) / 128, U / 128), 256, 0, stream>>>(x, Wx, bias, out);
    rnn_kernel<<<B, 512, 0, stream>>>(Wh, out);
}